// Round 1
// baseline (228009.277 us; speedup 1.0000x reference)
//
#include <hip/hip_runtime.h>
#include <hip/hip_cooperative_groups.h>

namespace cg = cooperative_groups;

#define VV    32000
#define EE    256
#define RSZ   1024
#define BB    64
#define TT    2048
#define NGRP  3
#define EPSLN 1e-5f

#define NBLK_PER_GRP 64
#define NBLK  (NBLK_PER_GRP * NGRP)   // 192 blocks, 1 per CU
#define NTHR  256

// states layout in d_ws: [layer(3)][slot(2)][B=64][R=1024] f32  -> 1.5 MB
__global__ __launch_bounds__(NTHR, 1)
void reservoir_main(const int*   __restrict__ x,        // [B,T]
                    const float* __restrict__ embed_w,  // [V,E]
                    const float* __restrict__ Win0,     // [E,R]
                    const float* __restrict__ Win1,     // [R,R]
                    const float* __restrict__ Win2,     // [R,R]
                    const float* __restrict__ Rm0,      // [R,R]
                    const float* __restrict__ Rm1,
                    const float* __restrict__ Rm2,
                    const float* __restrict__ ln_w,     // [R]
                    const float* __restrict__ ln_b,     // [R]
                    float*       __restrict__ states,   // [3][2][B][R]
                    float*       __restrict__ out)      // [B,R]
{
    cg::grid_group grid = cg::this_grid();

    const int blk  = blockIdx.x;
    const int grp  = blk / NBLK_PER_GRP;      // which layer this block serves
    const int gb   = blk % NBLK_PER_GRP;
    const int row0 = (gb >> 4) << 4;          // 0,16,32,48  (batch rows)
    const int col0 = (gb & 15) << 6;          // 0..960 step 64 (output cols)
    const int tid  = threadIdx.x;
    const int rr   = tid >> 4;                // 0..15 row within tile
    const int cgi  = tid & 15;                // 0..15 col-group (4 cols each)
    const int c    = col0 + (cgi << 2);
    const int row  = row0 + rr;

    const float* Wl = (grp == 0) ? Win0 : ((grp == 1) ? Win1 : Win2);
    const float* Rl = (grp == 0) ? Rm0  : ((grp == 1) ? Rm1  : Rm2);
    const int    K2 = (grp == 0) ? EE : RSZ;

    float* const sl = states + (size_t)grp * 2 * (BB * RSZ);

    for (int tick = 0; tick < TT + NGRP - 1; ++tick) {
        const int t = tick - grp;
        if (t >= 0 && t < TT) {
            // s_l(t-1): slot (t-1)&1 == (t+1)&1 ; t==0 reads the zeroed slot 1
            const float* sprev = sl + (size_t)((t + 1) & 1) * (BB * RSZ) + (size_t)row * RSZ;
            const float* curp;
            if (grp == 0) {
                curp = embed_w + (size_t)x[row * TT + t] * EE;
            } else {
                curp = states + ((size_t)(grp - 1) * 2 + (t & 1)) * (BB * RSZ) + (size_t)row * RSZ;
            }

            float a0 = 0.f, a1 = 0.f, a2 = 0.f, a3 = 0.f;

            // s_prev @ R_l   (K = 1024)
            {
                const float* bp = Rl + c;
                for (int k = 0; k < RSZ; k += 4) {
                    const float4 a4 = *reinterpret_cast<const float4*>(sprev + k);
                    const float av[4] = {a4.x, a4.y, a4.z, a4.w};
#pragma unroll
                    for (int j = 0; j < 4; ++j) {
                        const float4 w = *reinterpret_cast<const float4*>(bp + (size_t)(k + j) * RSZ);
                        a0 += av[j] * w.x;
                        a1 += av[j] * w.y;
                        a2 += av[j] * w.z;
                        a3 += av[j] * w.w;
                    }
                }
            }
            // cur @ W_l   (K = 256 for layer 0, else 1024)
            {
                const float* bp = Wl + c;
                for (int k = 0; k < K2; k += 4) {
                    const float4 a4 = *reinterpret_cast<const float4*>(curp + k);
                    const float av[4] = {a4.x, a4.y, a4.z, a4.w};
#pragma unroll
                    for (int j = 0; j < 4; ++j) {
                        const float4 w = *reinterpret_cast<const float4*>(bp + (size_t)(k + j) * RSZ);
                        a0 += av[j] * w.x;
                        a1 += av[j] * w.y;
                        a2 += av[j] * w.z;
                        a3 += av[j] * w.w;
                    }
                }
            }

            float* sout = sl + (size_t)(t & 1) * (BB * RSZ) + (size_t)row * RSZ + c;
            float4 o;
            o.x = tanhf(a0);
            o.y = tanhf(a1);
            o.z = tanhf(a2);
            o.w = tanhf(a3);
            *reinterpret_cast<float4*>(sout) = o;
        }
        grid.sync();
    }

    // LayerNorm over h = s_2(T-1)  (slot (T-1)&1 == 1), one block per batch row
    if (blk < BB) {
        const float* h = states + (size_t)(2 * 2 + ((TT - 1) & 1)) * (BB * RSZ) + (size_t)blk * RSZ;
        __shared__ float red[NTHR];

        float lsum = 0.f;
        for (int k = tid; k < RSZ; k += NTHR) lsum += h[k];
        red[tid] = lsum;
        __syncthreads();
        for (int s = NTHR / 2; s > 0; s >>= 1) {
            if (tid < s) red[tid] += red[tid + s];
            __syncthreads();
        }
        const float mu = red[0] / (float)RSZ;
        __syncthreads();

        float lvar = 0.f;
        for (int k = tid; k < RSZ; k += NTHR) {
            const float d = h[k] - mu;
            lvar += d * d;
        }
        red[tid] = lvar;
        __syncthreads();
        for (int s = NTHR / 2; s > 0; s >>= 1) {
            if (tid < s) red[tid] += red[tid + s];
            __syncthreads();
        }
        const float inv = rsqrtf(red[0] / (float)RSZ + EPSLN);

        for (int k = tid; k < RSZ; k += NTHR) {
            out[blk * RSZ + k] = (h[k] - mu) * inv * ln_w[k] + ln_b[k];
        }
    }
}

extern "C" void kernel_launch(void* const* d_in, const int* in_sizes, int n_in,
                              void* d_out, int out_size, void* d_ws, size_t ws_size,
                              hipStream_t stream) {
    const int*   x       = (const int*)  d_in[0];
    const float* embed_w = (const float*)d_in[1];
    const float* Win0    = (const float*)d_in[2];
    const float* Win1    = (const float*)d_in[3];
    const float* Win2    = (const float*)d_in[4];
    const float* Rm0     = (const float*)d_in[5];
    const float* Rm1     = (const float*)d_in[6];
    const float* Rm2     = (const float*)d_in[7];
    const float* ln_w    = (const float*)d_in[8];
    const float* ln_b    = (const float*)d_in[9];
    float*       out     = (float*)d_out;
    float*       states  = (float*)d_ws;

    // zero all state buffers (s(-1) = 0); deterministic every call
    hipMemsetAsync(d_ws, 0, (size_t)NGRP * 2 * BB * RSZ * sizeof(float), stream);

    void* args[] = {
        (void*)&x, (void*)&embed_w,
        (void*)&Win0, (void*)&Win1, (void*)&Win2,
        (void*)&Rm0, (void*)&Rm1, (void*)&Rm2,
        (void*)&ln_w, (void*)&ln_b,
        (void*)&states, (void*)&out
    };
    hipLaunchCooperativeKernel(reinterpret_cast<void*>(reservoir_main),
                               dim3(NBLK), dim3(NTHR), args, 0, stream);
}

// Round 2
// 119154.321 us; speedup vs baseline: 1.9136x; 1.9136x over previous
//
#include <hip/hip_runtime.h>
#include <hip/hip_cooperative_groups.h>

namespace cg = cooperative_groups;

#define VV    32000
#define EE    256
#define RSZ   1024
#define BB    64
#define TT    2048
#define NGRP  3
#define EPSLN 1e-5f

#define NBLK_PER_GRP 64
#define NBLK  (NBLK_PER_GRP * NGRP)   // 192 blocks, 1 per CU
#define NTHR  512                     // 8 waves = 8 k-groups of 64
#define SLAB  (BB * RSZ)              // 65536 floats per state slot
#define PROWS 17                      // padded row stride in pbuf (bank-conflict-free)

// d_ws: states [layer(3)][slot(2)][B=64][R=1024] f32 -> 1.5 MB
__global__ __launch_bounds__(NTHR, 1)
void reservoir_main(const int*   __restrict__ x,        // [B,T]
                    const float* __restrict__ embed_w,  // [V,E]
                    const float* __restrict__ Win0,     // [E,R]
                    const float* __restrict__ Win1,     // [R,R]
                    const float* __restrict__ Win2,     // [R,R]
                    const float* __restrict__ Rm0,      // [R,R]
                    const float* __restrict__ Rm1,
                    const float* __restrict__ Rm2,
                    const float* __restrict__ ln_w,     // [R]
                    const float* __restrict__ ln_b,     // [R]
                    float*       __restrict__ states,
                    float*       __restrict__ out)      // [B,R]
{
    cg::grid_group grid = cg::this_grid();

    const int blk  = blockIdx.x;
    const int grp  = blk / NBLK_PER_GRP;      // layer this block serves
    const int gb   = blk % NBLK_PER_GRP;
    const int c0   = gb * 16;                 // 16-column output slice
    const int tid  = threadIdx.x;
    const int kg   = tid >> 6;                // k-group 0..7 (== wave id)
    const int lane = tid & 63;
    const int rg   = lane >> 3;               // row-group 0..7 (8 rows each)
    const int cg_  = lane & 7;                // col-group 0..7 (2 cols each)

    const float* Wl = (grp == 0) ? Win0 : ((grp == 1) ? Win1 : Win2);
    const float* Rl = (grp == 0) ? Rm0  : ((grp == 1) ? Rm1  : Rm2);
    const int    Kw  = (grp == 0) ? EE : RSZ; // input-path K
    const int    Kw8 = Kw >> 3;               // per k-group slice of input path

    // LDS: weight slab [2048][16] f32 (R-part rows 0..1023, W-part rows 1024..)
    __shared__ float wlds[2048 * 16];         // 128 KB
    __shared__ float pbuf[4][64 * PROWS];     // 17 KB partial-sum tree buffer
    __shared__ float red[NTHR];               // 2 KB (LayerNorm)

    // ---- stage weights to LDS once (reused for all 2048 ticks) ----
    for (int idx = tid; idx < RSZ * 16; idx += NTHR) {
        const int k = idx >> 4, c = idx & 15;
        wlds[idx] = Rl[(size_t)k * RSZ + c0 + c];
    }
    for (int idx = tid; idx < Kw * 16; idx += NTHR) {
        const int k = idx >> 4, c = idx & 15;
        wlds[RSZ * 16 + idx] = Wl[(size_t)k * RSZ + c0 + c];
    }
    __syncthreads();

    float* const sl = states + (size_t)grp * 2 * SLAB;

    for (int tick = 0; tick < TT + NGRP - 1; ++tick) {
        const int t = tick - grp;             // uniform per block
        if (t >= 0 && t < TT) {
            const float* sprev = sl + (size_t)((t + 1) & 1) * SLAB;

            float acc[8][2];
#pragma unroll
            for (int i = 0; i < 8; ++i) { acc[i][0] = 0.f; acc[i][1] = 0.f; }

            // ---- recurrent part: s_prev @ R_l, k in [kg*128, kg*128+128) ----
            {
                const float* ap[8];
#pragma unroll
                for (int i = 0; i < 8; ++i)
                    ap[i] = sprev + (size_t)(rg * 8 + i) * RSZ;
                const int k0 = kg * 128, k1 = k0 + 128;
                for (int k = k0; k < k1; k += 4) {
                    float4 a4[8];
#pragma unroll
                    for (int i = 0; i < 8; ++i)
                        a4[i] = *reinterpret_cast<const float4*>(ap[i] + k);
#pragma unroll
                    for (int j = 0; j < 4; ++j) {
                        const float2 w2 = *reinterpret_cast<const float2*>(
                            &wlds[(k + j) * 16 + cg_ * 2]);
#pragma unroll
                        for (int i = 0; i < 8; ++i) {
                            const float av = reinterpret_cast<const float*>(&a4[i])[j];
                            acc[i][0] = fmaf(av, w2.x, acc[i][0]);
                            acc[i][1] = fmaf(av, w2.y, acc[i][1]);
                        }
                    }
                }
            }
            // ---- input part: cur @ W_l, kw in [kg*Kw8, kg*Kw8+Kw8) ----
            {
                const float* cp[8];
                if (grp == 0) {
#pragma unroll
                    for (int i = 0; i < 8; ++i) {
                        const int row = rg * 8 + i;
                        cp[i] = embed_w + (size_t)x[row * TT + t] * EE;
                    }
                } else {
                    const float* cbase = states + ((size_t)(grp - 1) * 2 + (t & 1)) * SLAB;
#pragma unroll
                    for (int i = 0; i < 8; ++i)
                        cp[i] = cbase + (size_t)(rg * 8 + i) * RSZ;
                }
                const int k0 = kg * Kw8, k1 = k0 + Kw8;
                for (int k = k0; k < k1; k += 4) {
                    float4 a4[8];
#pragma unroll
                    for (int i = 0; i < 8; ++i)
                        a4[i] = *reinterpret_cast<const float4*>(cp[i] + k);
#pragma unroll
                    for (int j = 0; j < 4; ++j) {
                        const float2 w2 = *reinterpret_cast<const float2*>(
                            &wlds[(RSZ + k + j) * 16 + cg_ * 2]);
#pragma unroll
                        for (int i = 0; i < 8; ++i) {
                            const float av = reinterpret_cast<const float*>(&a4[i])[j];
                            acc[i][0] = fmaf(av, w2.x, acc[i][0]);
                            acc[i][1] = fmaf(av, w2.y, acc[i][1]);
                        }
                    }
                }
            }

            // ---- tree-reduce the 8 k-group partials through LDS ----
            const int pbase = (rg * 8) * PROWS + cg_ * 2;
            if (kg >= 4) {
#pragma unroll
                for (int i = 0; i < 8; ++i)
                    *reinterpret_cast<float2*>(&pbuf[kg - 4][pbase + i * PROWS])
                        = make_float2(acc[i][0], acc[i][1]);
            }
            __syncthreads();
            if (kg < 4) {
#pragma unroll
                for (int i = 0; i < 8; ++i) {
                    const float2 p = *reinterpret_cast<const float2*>(&pbuf[kg][pbase + i * PROWS]);
                    acc[i][0] += p.x; acc[i][1] += p.y;
                }
            }
            __syncthreads();
            if (kg == 2 || kg == 3) {
#pragma unroll
                for (int i = 0; i < 8; ++i)
                    *reinterpret_cast<float2*>(&pbuf[kg - 2][pbase + i * PROWS])
                        = make_float2(acc[i][0], acc[i][1]);
            }
            __syncthreads();
            if (kg < 2) {
#pragma unroll
                for (int i = 0; i < 8; ++i) {
                    const float2 p = *reinterpret_cast<const float2*>(&pbuf[kg][pbase + i * PROWS]);
                    acc[i][0] += p.x; acc[i][1] += p.y;
                }
            }
            __syncthreads();
            if (kg == 1) {
#pragma unroll
                for (int i = 0; i < 8; ++i)
                    *reinterpret_cast<float2*>(&pbuf[0][pbase + i * PROWS])
                        = make_float2(acc[i][0], acc[i][1]);
            }
            __syncthreads();
            if (kg == 0) {
                float* sout = sl + (size_t)(t & 1) * SLAB;
#pragma unroll
                for (int i = 0; i < 8; ++i) {
                    const float2 p = *reinterpret_cast<const float2*>(&pbuf[0][pbase + i * PROWS]);
                    float2 o;
                    o.x = tanhf(acc[i][0] + p.x);
                    o.y = tanhf(acc[i][1] + p.y);
                    *reinterpret_cast<float2*>(sout + (size_t)(rg * 8 + i) * RSZ + c0 + cg_ * 2) = o;
                }
            }
        }
        grid.sync();
    }

    // ---- LayerNorm over h = s_2(T-1) (slot 1), one block per batch row ----
    if (blk < BB) {
        const float* h = states + (size_t)(2 * 2 + ((TT - 1) & 1)) * SLAB + (size_t)blk * RSZ;

        float lsum = 0.f;
        for (int k = tid; k < RSZ; k += NTHR) lsum += h[k];
        red[tid] = lsum;
        __syncthreads();
        for (int s = NTHR / 2; s > 0; s >>= 1) {
            if (tid < s) red[tid] += red[tid + s];
            __syncthreads();
        }
        const float mu = red[0] / (float)RSZ;
        __syncthreads();

        float lvar = 0.f;
        for (int k = tid; k < RSZ; k += NTHR) {
            const float d = h[k] - mu;
            lvar += d * d;
        }
        red[tid] = lvar;
        __syncthreads();
        for (int s = NTHR / 2; s > 0; s >>= 1) {
            if (tid < s) red[tid] += red[tid + s];
            __syncthreads();
        }
        const float inv = rsqrtf(red[0] / (float)RSZ + EPSLN);

        for (int k = tid; k < RSZ; k += NTHR) {
            out[blk * RSZ + k] = (h[k] - mu) * inv * ln_w[k] + ln_b[k];
        }
    }
}

extern "C" void kernel_launch(void* const* d_in, const int* in_sizes, int n_in,
                              void* d_out, int out_size, void* d_ws, size_t ws_size,
                              hipStream_t stream) {
    const int*   x       = (const int*)  d_in[0];
    const float* embed_w = (const float*)d_in[1];
    const float* Win0    = (const float*)d_in[2];
    const float* Win1    = (const float*)d_in[3];
    const float* Win2    = (const float*)d_in[4];
    const float* Rm0     = (const float*)d_in[5];
    const float* Rm1     = (const float*)d_in[6];
    const float* Rm2     = (const float*)d_in[7];
    const float* ln_w    = (const float*)d_in[8];
    const float* ln_b    = (const float*)d_in[9];
    float*       out     = (float*)d_out;
    float*       states  = (float*)d_ws;

    hipMemsetAsync(d_ws, 0, (size_t)NGRP * 2 * SLAB * sizeof(float), stream);

    void* args[] = {
        (void*)&x, (void*)&embed_w,
        (void*)&Win0, (void*)&Win1, (void*)&Win2,
        (void*)&Rm0, (void*)&Rm1, (void*)&Rm2,
        (void*)&ln_w, (void*)&ln_b,
        (void*)&states, (void*)&out
    };
    hipLaunchCooperativeKernel(reinterpret_cast<void*>(reservoir_main),
                               dim3(NBLK), dim3(NTHR), args, 0, stream);
}

// Round 3
// 86095.215 us; speedup vs baseline: 2.6483x; 1.3840x over previous
//
#include <hip/hip_runtime.h>

#define VV    32000
#define EE    256
#define RSZ   1024
#define BB    64
#define TT    2048
#define NGRP  3
#define EPSLN 1e-5f

#define NBLK_PER_GRP 64
#define NBLK  (NBLK_PER_GRP * NGRP)   // 192 blocks, 1 per CU
#define NTHR  1024                    // 16 waves = 8 k-groups x 128 threads
#define SLAB  (BB * RSZ)              // 65536 floats per state slot

// d_ws layout: states [3][2][64][1024] f32 (1.5 MB), then barrier counters
#define BAR_OFF (NGRP * 2 * SLAB)     // in floats

__device__ __forceinline__ void dot_slice(const float* a0, const float* a1,
                                          const float* a2, const float* a3,
                                          int k0, int k1, const float* wp,
                                          float (&acc)[4][2]) {
    float4 c0 = *reinterpret_cast<const float4*>(a0 + k0);
    float4 c1 = *reinterpret_cast<const float4*>(a1 + k0);
    float4 c2 = *reinterpret_cast<const float4*>(a2 + k0);
    float4 c3 = *reinterpret_cast<const float4*>(a3 + k0);
    int k = k0;
    for (; k < k1 - 4; k += 4) {
        float4 n0 = *reinterpret_cast<const float4*>(a0 + k + 4);
        float4 n1 = *reinterpret_cast<const float4*>(a1 + k + 4);
        float4 n2 = *reinterpret_cast<const float4*>(a2 + k + 4);
        float4 n3 = *reinterpret_cast<const float4*>(a3 + k + 4);
        const float* f0 = reinterpret_cast<const float*>(&c0);
        const float* f1 = reinterpret_cast<const float*>(&c1);
        const float* f2 = reinterpret_cast<const float*>(&c2);
        const float* f3 = reinterpret_cast<const float*>(&c3);
#pragma unroll
        for (int j = 0; j < 4; ++j) {
            const float2 w = *reinterpret_cast<const float2*>(wp + j * 16);
            acc[0][0] = fmaf(f0[j], w.x, acc[0][0]);
            acc[0][1] = fmaf(f0[j], w.y, acc[0][1]);
            acc[1][0] = fmaf(f1[j], w.x, acc[1][0]);
            acc[1][1] = fmaf(f1[j], w.y, acc[1][1]);
            acc[2][0] = fmaf(f2[j], w.x, acc[2][0]);
            acc[2][1] = fmaf(f2[j], w.y, acc[2][1]);
            acc[3][0] = fmaf(f3[j], w.x, acc[3][0]);
            acc[3][1] = fmaf(f3[j], w.y, acc[3][1]);
        }
        wp += 64;
        c0 = n0; c1 = n1; c2 = n2; c3 = n3;
    }
    {   // epilogue (no prefetch)
        const float* f0 = reinterpret_cast<const float*>(&c0);
        const float* f1 = reinterpret_cast<const float*>(&c1);
        const float* f2 = reinterpret_cast<const float*>(&c2);
        const float* f3 = reinterpret_cast<const float*>(&c3);
#pragma unroll
        for (int j = 0; j < 4; ++j) {
            const float2 w = *reinterpret_cast<const float2*>(wp + j * 16);
            acc[0][0] = fmaf(f0[j], w.x, acc[0][0]);
            acc[0][1] = fmaf(f0[j], w.y, acc[0][1]);
            acc[1][0] = fmaf(f1[j], w.x, acc[1][0]);
            acc[1][1] = fmaf(f1[j], w.y, acc[1][1]);
            acc[2][0] = fmaf(f2[j], w.x, acc[2][0]);
            acc[2][1] = fmaf(f2[j], w.y, acc[2][1]);
            acc[3][0] = fmaf(f3[j], w.x, acc[3][0]);
            acc[3][1] = fmaf(f3[j], w.y, acc[3][1]);
        }
    }
}

__global__ __launch_bounds__(NTHR, 4)
void reservoir_main(const int*   __restrict__ x,        // [B,T]
                    const float* __restrict__ embed_w,  // [V,E]
                    const float* __restrict__ Win0,
                    const float* __restrict__ Win1,
                    const float* __restrict__ Win2,
                    const float* __restrict__ Rm0,
                    const float* __restrict__ Rm1,
                    const float* __restrict__ Rm2,
                    const float* __restrict__ ln_w,
                    const float* __restrict__ ln_b,
                    float*       __restrict__ states,
                    unsigned*    __restrict__ bar,
                    float*       __restrict__ out)
{
    const int blk   = blockIdx.x;
    const int grp   = blk >> 6;              // layer
    const int gb    = blk & 63;
    const int c0    = gb << 4;               // 16-col slice
    const int tid   = threadIdx.x;
    const int kg    = tid >> 7;              // 0..7 (128 threads each)
    const int idx   = tid & 127;
    const int rbase = (idx >> 3) << 2;       // 0,4,...,60 (4 rows per lane)
    const int cg2   = (idx & 7) << 1;        // col pair base

    const float* Wl  = (grp == 0) ? Win0 : ((grp == 1) ? Win1 : Win2);
    const float* Rl  = (grp == 0) ? Rm0  : ((grp == 1) ? Rm1  : Rm2);
    const int    Kw  = (grp == 0) ? EE : RSZ;
    const int    Kw8 = Kw >> 3;

    __shared__ float wlds[2048 * 16];        // 128 KB weight slab
    __shared__ float pbuf[8][32][18];        // 18 KB partials (padded+swizzled)

    // ---- stage weights to LDS once ----
    for (int i = tid; i < RSZ * 16; i += NTHR) {
        const int k = i >> 4, c = i & 15;
        wlds[i] = Rl[(size_t)k * RSZ + c0 + c];
    }
    for (int i = tid; i < Kw * 16; i += NTHR) {
        const int k = i >> 4, c = i & 15;
        wlds[RSZ * 16 + i] = Wl[(size_t)k * RSZ + c0 + c];
    }
    __syncthreads();

    unsigned* arrive = bar;
    unsigned* epoch  = bar + 32;

    float* const sl = states + (size_t)grp * 2 * SLAB;

    for (int tick = 0; tick < TT + NGRP - 1; ++tick) {
        const int t = tick - grp;            // uniform per block
        if (0 <= t && t < TT) {
            const float* sprev = sl + (size_t)((t + 1) & 1) * SLAB;

            const float *cp0, *cp1, *cp2, *cp3;
            if (grp == 0) {
                cp0 = embed_w + (size_t)x[(rbase + 0) * TT + t] * EE;
                cp1 = embed_w + (size_t)x[(rbase + 1) * TT + t] * EE;
                cp2 = embed_w + (size_t)x[(rbase + 2) * TT + t] * EE;
                cp3 = embed_w + (size_t)x[(rbase + 3) * TT + t] * EE;
            } else {
                const float* cb = states + ((size_t)(grp - 1) * 2 + (t & 1)) * SLAB;
                cp0 = cb + (size_t)(rbase + 0) * RSZ;
                cp1 = cb + (size_t)(rbase + 1) * RSZ;
                cp2 = cb + (size_t)(rbase + 2) * RSZ;
                cp3 = cb + (size_t)(rbase + 3) * RSZ;
            }

            float acc[4][2] = {{0.f, 0.f}, {0.f, 0.f}, {0.f, 0.f}, {0.f, 0.f}};

            {   // recurrent: s_prev @ R_l, K-slice [kg*128, kg*128+128)
                const float* a0 = sprev + (size_t)(rbase + 0) * RSZ;
                const float* a1 = sprev + (size_t)(rbase + 1) * RSZ;
                const float* a2 = sprev + (size_t)(rbase + 2) * RSZ;
                const float* a3 = sprev + (size_t)(rbase + 3) * RSZ;
                const int k0 = kg << 7;
                dot_slice(a0, a1, a2, a3, k0, k0 + 128, wlds + k0 * 16 + cg2, acc);
            }
            {   // input: cur @ W_l, K-slice [kg*Kw8, kg*Kw8+Kw8)
                const int k0 = kg * Kw8;
                dot_slice(cp0, cp1, cp2, cp3, k0, k0 + Kw8,
                          wlds + (RSZ + k0) * 16 + cg2, acc);
            }

            // ---- flat reduce over 8 k-groups, two row-halves ----
            float* sout = sl + (size_t)(t & 1) * SLAB;

            if (rbase < 32) {
#pragma unroll
                for (int r = 0; r < 4; ++r) {
                    const int row = rbase + r;
                    *reinterpret_cast<float2*>(&pbuf[kg][row][cg2 ^ (row & 12)])
                        = make_float2(acc[r][0], acc[r][1]);
                }
            }
            __syncthreads();
            if (tid < 512) {
                const int row = tid >> 4, col = tid & 15;
                float s = 0.f;
#pragma unroll
                for (int g = 0; g < 8; ++g) s += pbuf[g][row][col ^ (row & 12)];
                sout[(size_t)row * RSZ + c0 + col] = tanhf(s);
            }
            __syncthreads();
            if (rbase >= 32) {
#pragma unroll
                for (int r = 0; r < 4; ++r) {
                    const int row = rbase + r, rl = row & 31;
                    *reinterpret_cast<float2*>(&pbuf[kg][rl][cg2 ^ (rl & 12)])
                        = make_float2(acc[r][0], acc[r][1]);
                }
            }
            __syncthreads();
            if (tid < 512) {
                const int rl = tid >> 4, col = tid & 15;
                float s = 0.f;
#pragma unroll
                for (int g = 0; g < 8; ++g) s += pbuf[g][rl][col ^ (rl & 12)];
                sout[(size_t)(32 + rl) * RSZ + c0 + col] = tanhf(s);
            }
        }

        // ---- custom device-wide barrier (monotonic epoch) ----
        __syncthreads();                     // drain this block's stores
        if (tid == 0) {
            __threadfence();                 // release: flush to coherence point
            const unsigned target = (unsigned)(tick + 1);
            const unsigned prev = atomicAdd(arrive, 1u);
            if (prev == (unsigned)NBLK * target - 1u) {
                __hip_atomic_store(epoch, target, __ATOMIC_RELEASE,
                                   __HIP_MEMORY_SCOPE_AGENT);
            } else {
                while (__hip_atomic_load(epoch, __ATOMIC_RELAXED,
                                         __HIP_MEMORY_SCOPE_AGENT) < target)
                    __builtin_amdgcn_s_sleep(2);
            }
            __threadfence();                 // acquire: invalidate stale lines
        }
        __syncthreads();
    }

    // ---- LayerNorm over h = s_2(T-1) (slot 1), blocks 0..63, 1 row each ----
    if (blk < BB) {
        const float* h = states + ((size_t)2 * 2 + 1) * SLAB + (size_t)blk * RSZ;
        float* red = &pbuf[0][0][0];

        const float hv = h[tid];             // RSZ == NTHR
        float v = hv;
#pragma unroll
        for (int o = 32; o > 0; o >>= 1) v += __shfl_down(v, o, 64);
        if ((tid & 63) == 0) red[tid >> 6] = v;
        __syncthreads();
        if (tid == 0) {
            float s = 0.f;
#pragma unroll
            for (int i = 0; i < 16; ++i) s += red[i];
            red[20] = s / (float)RSZ;
        }
        __syncthreads();
        const float mu = red[20];
        const float d = hv - mu;
        v = d * d;
#pragma unroll
        for (int o = 32; o > 0; o >>= 1) v += __shfl_down(v, o, 64);
        __syncthreads();
        if ((tid & 63) == 0) red[tid >> 6] = v;
        __syncthreads();
        if (tid == 0) {
            float s = 0.f;
#pragma unroll
            for (int i = 0; i < 16; ++i) s += red[i];
            red[21] = rsqrtf(s / (float)RSZ + EPSLN);
        }
        __syncthreads();
        const float inv = red[21];
        out[blk * RSZ + tid] = d * inv * ln_w[tid] + ln_b[tid];
    }
}

extern "C" void kernel_launch(void* const* d_in, const int* in_sizes, int n_in,
                              void* d_out, int out_size, void* d_ws, size_t ws_size,
                              hipStream_t stream) {
    const int*   x       = (const int*)  d_in[0];
    const float* embed_w = (const float*)d_in[1];
    const float* Win0    = (const float*)d_in[2];
    const float* Win1    = (const float*)d_in[3];
    const float* Win2    = (const float*)d_in[4];
    const float* Rm0     = (const float*)d_in[5];
    const float* Rm1     = (const float*)d_in[6];
    const float* Rm2     = (const float*)d_in[7];
    const float* ln_w    = (const float*)d_in[8];
    const float* ln_b    = (const float*)d_in[9];
    float*       out     = (float*)d_out;
    float*       states  = (float*)d_ws;
    unsigned*    bar     = (unsigned*)((float*)d_ws + BAR_OFF);

    // zero states (s(-1)=0) AND barrier counters; deterministic every call
    hipMemsetAsync(d_ws, 0, (size_t)BAR_OFF * sizeof(float) + 4096, stream);

    void* args[] = {
        (void*)&x, (void*)&embed_w,
        (void*)&Win0, (void*)&Win1, (void*)&Win2,
        (void*)&Rm0, (void*)&Rm1, (void*)&Rm2,
        (void*)&ln_w, (void*)&ln_b,
        (void*)&states, (void*)&bar, (void*)&out
    };
    hipLaunchCooperativeKernel(reinterpret_cast<void*>(reservoir_main),
                               dim3(NBLK), dim3(NTHR), args, 0, stream);
}